// Round 1
// baseline (1973.632 us; speedup 1.0000x reference)
//
#include <hip/hip_runtime.h>
#include <math.h>

#define NN 100000
#define NE 1600000
#define NG 1000
#define BN_EPS 1e-5f
#define SCAN_BLK 256
#define NSCAN ((NN + SCAN_BLK - 1) / SCAN_BLK)   // 391

// ---------------- CSR build ----------------

__global__ __launch_bounds__(256) void k_init(float* pooled, float* stats, int* cnt) {
    int i = blockIdx.x * blockDim.x + threadIdx.x;
    int stride = gridDim.x * blockDim.x;
    for (int j = i; j < 5 * NG * 64; j += stride) pooled[j] = 0.f;
    for (int j = i; j < 1024; j += stride) stats[j] = 0.f;
    for (int j = i; j < NN; j += stride) cnt[j] = 0;
}

__global__ __launch_bounds__(256) void k_hist(const int* __restrict__ dst, int* __restrict__ cnt) {
    int i = blockIdx.x * blockDim.x + threadIdx.x;
    int stride = gridDim.x * blockDim.x;
    for (int e = i; e < NE; e += stride) atomicAdd(&cnt[dst[e]], 1);
}

__global__ __launch_bounds__(SCAN_BLK) void k_scanA(const int* __restrict__ cnt,
                                                    int* __restrict__ off,
                                                    int* __restrict__ bsum) {
    __shared__ int s[SCAN_BLK];
    int t = threadIdx.x;
    int i = blockIdx.x * SCAN_BLK + t;
    int v = (i < NN) ? cnt[i] : 0;
    s[t] = v;
    __syncthreads();
    for (int o = 1; o < SCAN_BLK; o <<= 1) {
        int x = (t >= o) ? s[t - o] : 0;
        __syncthreads();
        s[t] += x;
        __syncthreads();
    }
    if (i < NN) off[i] = s[t] - v;            // exclusive within block
    if (t == SCAN_BLK - 1) bsum[blockIdx.x] = s[t];
}

__global__ __launch_bounds__(512) void k_scanB(int* __restrict__ bsum) {
    __shared__ int s[512];
    int t = threadIdx.x;
    int v = (t < NSCAN) ? bsum[t] : 0;
    s[t] = v;
    __syncthreads();
    for (int o = 1; o < 512; o <<= 1) {
        int x = (t >= o) ? s[t - o] : 0;
        __syncthreads();
        s[t] += x;
        __syncthreads();
    }
    if (t < NSCAN) bsum[t] = s[t] - v;        // exclusive block offsets
}

__global__ __launch_bounds__(256) void k_scanC(int* __restrict__ off, const int* __restrict__ bsum,
                                               int* __restrict__ cur) {
    int i = blockIdx.x * blockDim.x + threadIdx.x;
    int stride = gridDim.x * blockDim.x;
    for (int j = i; j < NN; j += stride) {
        int o = off[j] + bsum[j / SCAN_BLK];
        off[j] = o;
        cur[j] = o;
    }
}

__global__ __launch_bounds__(256) void k_scatter(const int* __restrict__ src, const int* __restrict__ dst,
                                                 int* __restrict__ cur, int* __restrict__ csr) {
    int i = blockIdx.x * blockDim.x + threadIdx.x;
    int stride = gridDim.x * blockDim.x;
    for (int e = i; e < NE; e += stride) {
        int d = dst[e];
        int p = atomicAdd(&cur[d], 1);
        csr[p] = src[e];
    }
}

// ---------------- fused layer kernels ----------------
// Wave-per-row GEMM: lane = output column; W column in 64 VGPRs; row broadcast
// via per-wave LDS float4 reads.

__global__ __launch_bounds__(256) void k_agg_g1(
    const float* __restrict__ h, const int* __restrict__ csr,
    const int* __restrict__ off, const int* __restrict__ cnt,
    const float* __restrict__ W1, float* __restrict__ y,
    float* __restrict__ stats1,
    const int* __restrict__ gid, float* __restrict__ pool0)
{
    __shared__ __align__(16) float buf[4][64];
    int lane = threadIdx.x & 63;
    int wslot = threadIdx.x >> 6;
    int wid = blockIdx.x * (blockDim.x >> 6) + wslot;
    int nw = gridDim.x * (blockDim.x >> 6);
    int chunk = (NN + nw - 1) / nw;
    int n0 = wid * chunk, n1 = min(NN, n0 + chunk);

    float Wc[64];
#pragma unroll
    for (int k = 0; k < 64; k++) Wc[k] = W1[k * 64 + lane];

    float ls = 0.f, lss = 0.f;
    int curg = -1;
    float pacc = 0.f;

    for (int n = n0; n < n1; ++n) {
        float acc = h[(size_t)n * 64 + lane];
        if (pool0) {
            int g = gid[n];
            if (g != curg) {
                if (curg >= 0) atomicAdd(&pool0[curg * 64 + lane], pacc);
                curg = g; pacc = 0.f;
            }
            pacc += acc;
        }
        int s0 = off[n], d = cnt[n];
        for (int j = 0; j < d; ++j) {
            int s = csr[s0 + j];
            acc += h[(size_t)s * 64 + lane];
        }
        buf[wslot][lane] = acc;
        float yl = 0.f;
#pragma unroll
        for (int k = 0; k < 16; k++) {
            float4 z4 = *(const float4*)&buf[wslot][k * 4];
            yl += z4.x * Wc[4 * k] + z4.y * Wc[4 * k + 1] + z4.z * Wc[4 * k + 2] + z4.w * Wc[4 * k + 3];
        }
        y[(size_t)n * 64 + lane] = yl;
        ls += yl;
        lss += yl * yl;
    }
    if (pool0 && curg >= 0) atomicAdd(&pool0[curg * 64 + lane], pacc);
    if (n0 < n1) {
        atomicAdd(&stats1[lane], ls);
        atomicAdd(&stats1[64 + lane], lss);
    }
}

__global__ __launch_bounds__(256) void k_g2(
    const float* __restrict__ y, const float* __restrict__ stats1,
    const float* __restrict__ g1, const float* __restrict__ b1,
    const float* __restrict__ W2, float* __restrict__ z,
    float* __restrict__ stats2)
{
    __shared__ __align__(16) float buf[4][64];
    int lane = threadIdx.x & 63;
    int wslot = threadIdx.x >> 6;
    int wid = blockIdx.x * (blockDim.x >> 6) + wslot;
    int nw = gridDim.x * (blockDim.x >> 6);
    int chunk = (NN + nw - 1) / nw;
    int n0 = wid * chunk, n1 = min(NN, n0 + chunk);

    float mean = stats1[lane] * (1.f / NN);
    float var  = stats1[64 + lane] * (1.f / NN) - mean * mean;
    float sc = rsqrtf(var + BN_EPS) * g1[lane];
    float sh = b1[lane] - mean * sc;

    float Wc[64];
#pragma unroll
    for (int k = 0; k < 64; k++) Wc[k] = W2[k * 64 + lane];

    float ls = 0.f, lss = 0.f;
    for (int n = n0; n < n1; ++n) {
        float v = y[(size_t)n * 64 + lane] * sc + sh;
        v = fmaxf(v, 0.f);
        buf[wslot][lane] = v;
        float zl = 0.f;
#pragma unroll
        for (int k = 0; k < 16; k++) {
            float4 t4 = *(const float4*)&buf[wslot][k * 4];
            zl += t4.x * Wc[4 * k] + t4.y * Wc[4 * k + 1] + t4.z * Wc[4 * k + 2] + t4.w * Wc[4 * k + 3];
        }
        z[(size_t)n * 64 + lane] = zl;
        ls += zl;
        lss += zl * zl;
    }
    if (n0 < n1) {
        atomicAdd(&stats2[lane], ls);
        atomicAdd(&stats2[64 + lane], lss);
    }
}

__global__ __launch_bounds__(256) void k_a2(
    float* __restrict__ z /* in-place: reads z2, writes h */,
    const float* __restrict__ stats2,
    const float* __restrict__ g2, const float* __restrict__ b2,
    const int* __restrict__ gid, float* __restrict__ pool)
{
    int lane = threadIdx.x & 63;
    int wslot = threadIdx.x >> 6;
    int wid = blockIdx.x * (blockDim.x >> 6) + wslot;
    int nw = gridDim.x * (blockDim.x >> 6);
    int chunk = (NN + nw - 1) / nw;
    int n0 = wid * chunk, n1 = min(NN, n0 + chunk);

    float mean = stats2[lane] * (1.f / NN);
    float var  = stats2[64 + lane] * (1.f / NN) - mean * mean;
    float sc = rsqrtf(var + BN_EPS) * g2[lane];
    float sh = b2[lane] - mean * sc;

    int curg = -1;
    float pacc = 0.f;
    for (int n = n0; n < n1; ++n) {
        float v = z[(size_t)n * 64 + lane] * sc + sh;
        v = fmaxf(v, 0.f);
        z[(size_t)n * 64 + lane] = v;
        int g = gid[n];
        if (g != curg) {
            if (curg >= 0) atomicAdd(&pool[curg * 64 + lane], pacc);
            curg = g; pacc = 0.f;
        }
        pacc += v;
    }
    if (curg >= 0) atomicAdd(&pool[curg * 64 + lane], pacc);
}

// ---------------- epilogue: score + log_softmax ----------------

__global__ __launch_bounds__(256) void k_final(
    const float* __restrict__ pooled, const float* __restrict__ pW,
    const float* __restrict__ pb, float* __restrict__ out)
{
    int t = blockIdx.x * blockDim.x + threadIdx.x;
    int g = t >> 4;
    int c = t & 15;
    if (g >= NG) return;
    float acc = 0.f;
#pragma unroll
    for (int i = 0; i < 5; i++) {
        const float* P = pooled + (size_t)i * NG * 64 + g * 64;
        const float* W = pW + i * 64 * 16;
        float a = 0.f;
#pragma unroll
        for (int k = 0; k < 64; k++) a += P[k] * W[k * 16 + c];
        acc += a + pb[i * 16 + c];
    }
    float m = acc;
    for (int o = 1; o < 16; o <<= 1) m = fmaxf(m, __shfl_xor(m, o, 16));
    float e = expf(acc - m);
    float s = e;
    for (int o = 1; o < 16; o <<= 1) s += __shfl_xor(s, o, 16);
    out[g * 16 + c] = acc - m - logf(s);
}

// ---------------- launch ----------------

extern "C" void kernel_launch(void* const* d_in, const int* in_sizes, int n_in,
                              void* d_out, int out_size, void* d_ws, size_t ws_size,
                              hipStream_t stream) {
    const float* feat = (const float*)d_in[0];
    const float* W1   = (const float*)d_in[1];
    const float* W2   = (const float*)d_in[2];
    const float* bn1g = (const float*)d_in[3];
    const float* bn1b = (const float*)d_in[4];
    const float* bn2g = (const float*)d_in[5];
    const float* bn2b = (const float*)d_in[6];
    const float* pW   = (const float*)d_in[7];
    const float* pb   = (const float*)d_in[8];
    const int* src = (const int*)d_in[9];
    const int* dst = (const int*)d_in[10];
    const int* gid = (const int*)d_in[11];
    float* out = (float*)d_out;

    char* ws = (char*)d_ws;
    size_t o = 0;
    auto alloc = [&](size_t bytes) {
        void* p = ws + o;
        o += (bytes + 255) & ~(size_t)255;
        return p;
    };
    float* hbuf   = (float*)alloc((size_t)NN * 64 * 4);   // h (and z2 in-place)
    float* ybuf   = (float*)alloc((size_t)NN * 64 * 4);
    float* pooled = (float*)alloc((size_t)5 * NG * 64 * 4);
    float* stats  = (float*)alloc(1024 * 4);
    int* cnt  = (int*)alloc((size_t)NN * 4);
    int* off  = (int*)alloc((size_t)NN * 4);
    int* cur  = (int*)alloc((size_t)NN * 4);
    int* csr  = (int*)alloc((size_t)NE * 4);
    int* bsum = (int*)alloc(512 * 4);

    // CSR build
    k_init<<<512, 256, 0, stream>>>(pooled, stats, cnt);
    k_hist<<<2048, 256, 0, stream>>>(dst, cnt);
    k_scanA<<<NSCAN, SCAN_BLK, 0, stream>>>(cnt, off, bsum);
    k_scanB<<<1, 512, 0, stream>>>(bsum);
    k_scanC<<<512, 256, 0, stream>>>(off, bsum, cur);
    k_scatter<<<2048, 256, 0, stream>>>(src, dst, cur, csr);

    const float* hin = feat;
    for (int L = 0; L < 4; ++L) {
        float* s1 = stats + L * 256;
        float* s2 = s1 + 128;
        k_agg_g1<<<1024, 256, 0, stream>>>(hin, csr, off, cnt, W1 + L * 4096, ybuf, s1,
                                           gid, (L == 0) ? pooled : nullptr);
        k_g2<<<1024, 256, 0, stream>>>(ybuf, s1, bn1g + L * 64, bn1b + L * 64,
                                       W2 + L * 4096, hbuf, s2);
        k_a2<<<1024, 256, 0, stream>>>(hbuf, s2, bn2g + L * 64, bn2b + L * 64,
                                       gid, pooled + (size_t)(L + 1) * NG * 64);
        hin = hbuf;
    }
    k_final<<<(NG * 16 + 255) / 256, 256, 0, stream>>>(pooled, pW, pb, out);
}

// Round 2
// 940.476 us; speedup vs baseline: 2.0985x; 2.0985x over previous
//
#include <hip/hip_runtime.h>
#include <math.h>

#define NN 100000
#define NE 1600000
#define NG 1000
#define BN_EPS 1e-5f
#define SCAN_BLK 256
#define NSCAN ((NN + SCAN_BLK - 1) / SCAN_BLK)   // 391
#define AGG_BLOCKS 2048
#define CAP 512   // per-wave LDS index cache (ints); chunk mean ~208, +21 sigma

// ---------------- CSR build ----------------

__global__ __launch_bounds__(256) void k_init(float* pooled, float* stats, int* cnt) {
    int i = blockIdx.x * blockDim.x + threadIdx.x;
    int stride = gridDim.x * blockDim.x;
    for (int j = i; j < 5 * NG * 64; j += stride) pooled[j] = 0.f;
    for (int j = i; j < 1024; j += stride) stats[j] = 0.f;
    for (int j = i; j < NN; j += stride) cnt[j] = 0;
}

__global__ __launch_bounds__(256) void k_hist(const int* __restrict__ dst, int* __restrict__ cnt) {
    int i = blockIdx.x * blockDim.x + threadIdx.x;
    int stride = gridDim.x * blockDim.x;
    for (int e = i; e < NE; e += stride) atomicAdd(&cnt[dst[e]], 1);
}

__global__ __launch_bounds__(SCAN_BLK) void k_scanA(const int* __restrict__ cnt,
                                                    int* __restrict__ off,
                                                    int* __restrict__ bsum) {
    __shared__ int s[SCAN_BLK];
    int t = threadIdx.x;
    int i = blockIdx.x * SCAN_BLK + t;
    int v = (i < NN) ? cnt[i] : 0;
    s[t] = v;
    __syncthreads();
    for (int o = 1; o < SCAN_BLK; o <<= 1) {
        int x = (t >= o) ? s[t - o] : 0;
        __syncthreads();
        s[t] += x;
        __syncthreads();
    }
    if (i < NN) off[i] = s[t] - v;
    if (t == SCAN_BLK - 1) bsum[blockIdx.x] = s[t];
}

__global__ __launch_bounds__(512) void k_scanB(int* __restrict__ bsum) {
    __shared__ int s[512];
    int t = threadIdx.x;
    int v = (t < NSCAN) ? bsum[t] : 0;
    s[t] = v;
    __syncthreads();
    for (int o = 1; o < 512; o <<= 1) {
        int x = (t >= o) ? s[t - o] : 0;
        __syncthreads();
        s[t] += x;
        __syncthreads();
    }
    if (t < NSCAN) bsum[t] = s[t] - v;
}

__global__ __launch_bounds__(256) void k_scanC(int* __restrict__ off, const int* __restrict__ bsum,
                                               int* __restrict__ cur) {
    int i = blockIdx.x * blockDim.x + threadIdx.x;
    int stride = gridDim.x * blockDim.x;
    for (int j = i; j < NN; j += stride) {
        int o = off[j] + bsum[j / SCAN_BLK];
        off[j] = o;
        cur[j] = o;
    }
    if (i == 0) off[NN] = NE;   // sentinel
}

__global__ __launch_bounds__(256) void k_scatter(const int* __restrict__ src, const int* __restrict__ dst,
                                                 int* __restrict__ cur, int* __restrict__ csr) {
    int i = blockIdx.x * blockDim.x + threadIdx.x;
    int stride = gridDim.x * blockDim.x;
    for (int e = i; e < NE; e += stride) {
        int d = dst[e];
        int p = atomicAdd(&cur[d], 1);
        csr[p] = src[e];
    }
}

// ---------------- fused layer kernels ----------------

__global__ __launch_bounds__(256) void k_agg_g1(
    const float* __restrict__ h, const int* __restrict__ csr,
    const int* __restrict__ off,
    const float* __restrict__ W1, float* __restrict__ y,
    float* __restrict__ stats1,
    const int* __restrict__ gid, float* __restrict__ pool0)
{
    __shared__ __align__(16) float buf[4][64];
    __shared__ int sidx[4][CAP];
    __shared__ float sred[128];
    int lane = threadIdx.x & 63;
    int wslot = threadIdx.x >> 6;
    int wid = blockIdx.x * 4 + wslot;
    int nw = AGG_BLOCKS * 4;
    int chunk = (NN + nw - 1) / nw;
    int n0 = wid * chunk, n1 = min(NN, n0 + chunk);

    float Wc[64];
#pragma unroll
    for (int k = 0; k < 64; k++) Wc[k] = W1[k * 64 + lane];

    float ls = 0.f, lss = 0.f;

    if (n0 < n1) {
        // cooperatively cache this wave's contiguous csr slice in LDS
        int e0 = off[n0];
        int eEnd = off[n1];
        int tot = eEnd - e0;
        int lim = min(tot, CAP);
        for (int t = lane; t < lim; t += 64) sidx[wslot][t] = csr[e0 + t];

        int curg = -1;
        float pacc = 0.f;

        for (int n = n0; n < n1; ++n) {
            float acc = h[(size_t)n * 64 + lane];
            if (pool0) {
                int g = gid[n];
                if (g != curg) {
                    if (curg >= 0) atomicAdd(&pool0[curg * 64 + lane], pacc);
                    curg = g; pacc = 0.f;
                }
                pacc += acc;
            }
            int s0 = off[n] - e0, s1 = off[n + 1] - e0;
            float a1 = 0.f, a2 = 0.f, a3 = 0.f;
            int j = s0;
            if (s1 <= lim) {
                for (; j + 4 <= s1; j += 4) {
                    int i0 = sidx[wslot][j],     i1 = sidx[wslot][j + 1],
                        i2 = sidx[wslot][j + 2], i3 = sidx[wslot][j + 3];
                    float v0 = h[(size_t)i0 * 64 + lane];
                    float v1 = h[(size_t)i1 * 64 + lane];
                    float v2 = h[(size_t)i2 * 64 + lane];
                    float v3 = h[(size_t)i3 * 64 + lane];
                    acc += v0; a1 += v1; a2 += v2; a3 += v3;
                }
                for (; j < s1; ++j) acc += h[(size_t)sidx[wslot][j] * 64 + lane];
            } else {
                for (; j + 4 <= s1; j += 4) {
                    int i0 = csr[e0 + j],     i1 = csr[e0 + j + 1],
                        i2 = csr[e0 + j + 2], i3 = csr[e0 + j + 3];
                    float v0 = h[(size_t)i0 * 64 + lane];
                    float v1 = h[(size_t)i1 * 64 + lane];
                    float v2 = h[(size_t)i2 * 64 + lane];
                    float v3 = h[(size_t)i3 * 64 + lane];
                    acc += v0; a1 += v1; a2 += v2; a3 += v3;
                }
                for (; j < s1; ++j) acc += h[(size_t)csr[e0 + j] * 64 + lane];
            }
            acc += (a1 + a2) + a3;

            buf[wslot][lane] = acc;
            float yl = 0.f;
#pragma unroll
            for (int k = 0; k < 16; k++) {
                float4 z4 = *(const float4*)&buf[wslot][k * 4];
                yl = fmaf(z4.x, Wc[4 * k], yl);
                yl = fmaf(z4.y, Wc[4 * k + 1], yl);
                yl = fmaf(z4.z, Wc[4 * k + 2], yl);
                yl = fmaf(z4.w, Wc[4 * k + 3], yl);
            }
            y[(size_t)n * 64 + lane] = yl;
            ls += yl;
            lss += yl * yl;
        }
        if (pool0 && curg >= 0) atomicAdd(&pool0[curg * 64 + lane], pacc);
    }

    if (threadIdx.x < 128) sred[threadIdx.x] = 0.f;
    __syncthreads();
    atomicAdd(&sred[lane], ls);
    atomicAdd(&sred[64 + lane], lss);
    __syncthreads();
    if (threadIdx.x < 128) atomicAdd(&stats1[threadIdx.x], sred[threadIdx.x]);
}

__global__ __launch_bounds__(256) void k_g2(
    const float* __restrict__ y, const float* __restrict__ stats1,
    const float* __restrict__ g1, const float* __restrict__ b1,
    const float* __restrict__ W2, float* __restrict__ z,
    float* __restrict__ stats2)
{
    __shared__ __align__(16) float buf[4][4][64];
    __shared__ float sred[128];
    int lane = threadIdx.x & 63;
    int wslot = threadIdx.x >> 6;
    int wid = blockIdx.x * 4 + wslot;
    int nw = AGG_BLOCKS * 4;
    int chunk = (NN + nw - 1) / nw;
    int n0 = wid * chunk, n1 = min(NN, n0 + chunk);

    float mean = stats1[lane] * (1.f / NN);
    float var  = stats1[64 + lane] * (1.f / NN) - mean * mean;
    float sc = rsqrtf(var + BN_EPS) * g1[lane];
    float sh = b1[lane] - mean * sc;

    float Wc[64];
#pragma unroll
    for (int k = 0; k < 64; k++) Wc[k] = W2[k * 64 + lane];

    float ls = 0.f, lss = 0.f;
    if (n0 < n1) {
        int n = n0;
        for (; n + 4 <= n1; n += 4) {
            float v0 = fmaxf(fmaf(y[(size_t)n * 64 + lane], sc, sh), 0.f);
            float v1 = fmaxf(fmaf(y[(size_t)(n + 1) * 64 + lane], sc, sh), 0.f);
            float v2 = fmaxf(fmaf(y[(size_t)(n + 2) * 64 + lane], sc, sh), 0.f);
            float v3 = fmaxf(fmaf(y[(size_t)(n + 3) * 64 + lane], sc, sh), 0.f);
            buf[wslot][0][lane] = v0;
            buf[wslot][1][lane] = v1;
            buf[wslot][2][lane] = v2;
            buf[wslot][3][lane] = v3;
#pragma unroll
            for (int r = 0; r < 4; ++r) {
                float zl = 0.f;
#pragma unroll
                for (int k = 0; k < 16; k++) {
                    float4 t4 = *(const float4*)&buf[wslot][r][k * 4];
                    zl = fmaf(t4.x, Wc[4 * k], zl);
                    zl = fmaf(t4.y, Wc[4 * k + 1], zl);
                    zl = fmaf(t4.z, Wc[4 * k + 2], zl);
                    zl = fmaf(t4.w, Wc[4 * k + 3], zl);
                }
                z[(size_t)(n + r) * 64 + lane] = zl;
                ls += zl;
                lss += zl * zl;
            }
        }
        for (; n < n1; ++n) {
            float v = fmaxf(fmaf(y[(size_t)n * 64 + lane], sc, sh), 0.f);
            buf[wslot][0][lane] = v;
            float zl = 0.f;
#pragma unroll
            for (int k = 0; k < 16; k++) {
                float4 t4 = *(const float4*)&buf[wslot][0][k * 4];
                zl = fmaf(t4.x, Wc[4 * k], zl);
                zl = fmaf(t4.y, Wc[4 * k + 1], zl);
                zl = fmaf(t4.z, Wc[4 * k + 2], zl);
                zl = fmaf(t4.w, Wc[4 * k + 3], zl);
            }
            z[(size_t)n * 64 + lane] = zl;
            ls += zl;
            lss += zl * zl;
        }
    }

    if (threadIdx.x < 128) sred[threadIdx.x] = 0.f;
    __syncthreads();
    atomicAdd(&sred[lane], ls);
    atomicAdd(&sred[64 + lane], lss);
    __syncthreads();
    if (threadIdx.x < 128) atomicAdd(&stats2[threadIdx.x], sred[threadIdx.x]);
}

__global__ __launch_bounds__(256) void k_a2(
    float* __restrict__ z,
    const float* __restrict__ stats2,
    const float* __restrict__ g2, const float* __restrict__ b2,
    const int* __restrict__ gid, float* __restrict__ pool)
{
    int lane = threadIdx.x & 63;
    int wslot = threadIdx.x >> 6;
    int wid = blockIdx.x * 4 + wslot;
    int nw = AGG_BLOCKS * 4;
    int chunk = (NN + nw - 1) / nw;
    int n0 = wid * chunk, n1 = min(NN, n0 + chunk);
    if (n0 >= n1) return;

    float mean = stats2[lane] * (1.f / NN);
    float var  = stats2[64 + lane] * (1.f / NN) - mean * mean;
    float sc = rsqrtf(var + BN_EPS) * g2[lane];
    float sh = b2[lane] - mean * sc;

    int curg = -1;
    float pacc = 0.f;
    int n = n0;
    for (; n + 4 <= n1; n += 4) {
        float z0 = z[(size_t)n * 64 + lane];
        float z1 = z[(size_t)(n + 1) * 64 + lane];
        float z2v = z[(size_t)(n + 2) * 64 + lane];
        float z3 = z[(size_t)(n + 3) * 64 + lane];
        int g0 = gid[n], g1v = gid[n + 1], g2v = gid[n + 2], g3 = gid[n + 3];
        float vv[4] = {z0, z1, z2v, z3};
        int gg[4] = {g0, g1v, g2v, g3};
#pragma unroll
        for (int r = 0; r < 4; ++r) {
            float v = fmaxf(fmaf(vv[r], sc, sh), 0.f);
            z[(size_t)(n + r) * 64 + lane] = v;
            if (gg[r] != curg) {
                if (curg >= 0) atomicAdd(&pool[curg * 64 + lane], pacc);
                curg = gg[r]; pacc = 0.f;
            }
            pacc += v;
        }
    }
    for (; n < n1; ++n) {
        float v = fmaxf(fmaf(z[(size_t)n * 64 + lane], sc, sh), 0.f);
        z[(size_t)n * 64 + lane] = v;
        int g = gid[n];
        if (g != curg) {
            if (curg >= 0) atomicAdd(&pool[curg * 64 + lane], pacc);
            curg = g; pacc = 0.f;
        }
        pacc += v;
    }
    if (curg >= 0) atomicAdd(&pool[curg * 64 + lane], pacc);
}

// ---------------- epilogue ----------------

__global__ __launch_bounds__(256) void k_final(
    const float* __restrict__ pooled, const float* __restrict__ pW,
    const float* __restrict__ pb, float* __restrict__ out)
{
    int t = blockIdx.x * blockDim.x + threadIdx.x;
    int g = t >> 4;
    int c = t & 15;
    if (g >= NG) return;
    float acc = 0.f;
#pragma unroll
    for (int i = 0; i < 5; i++) {
        const float* P = pooled + (size_t)i * NG * 64 + g * 64;
        const float* W = pW + i * 64 * 16;
        float a = 0.f;
#pragma unroll
        for (int k = 0; k < 64; k++) a += P[k] * W[k * 16 + c];
        acc += a + pb[i * 16 + c];
    }
    float m = acc;
    for (int o = 1; o < 16; o <<= 1) m = fmaxf(m, __shfl_xor(m, o, 16));
    float e = expf(acc - m);
    float s = e;
    for (int o = 1; o < 16; o <<= 1) s += __shfl_xor(s, o, 16);
    out[g * 16 + c] = acc - m - logf(s);
}

// ---------------- launch ----------------

extern "C" void kernel_launch(void* const* d_in, const int* in_sizes, int n_in,
                              void* d_out, int out_size, void* d_ws, size_t ws_size,
                              hipStream_t stream) {
    const float* feat = (const float*)d_in[0];
    const float* W1   = (const float*)d_in[1];
    const float* W2   = (const float*)d_in[2];
    const float* bn1g = (const float*)d_in[3];
    const float* bn1b = (const float*)d_in[4];
    const float* bn2g = (const float*)d_in[5];
    const float* bn2b = (const float*)d_in[6];
    const float* pW   = (const float*)d_in[7];
    const float* pb   = (const float*)d_in[8];
    const int* src = (const int*)d_in[9];
    const int* dst = (const int*)d_in[10];
    const int* gid = (const int*)d_in[11];
    float* out = (float*)d_out;

    char* ws = (char*)d_ws;
    size_t o = 0;
    auto alloc = [&](size_t bytes) {
        void* p = ws + o;
        o += (bytes + 255) & ~(size_t)255;
        return p;
    };
    float* hbuf   = (float*)alloc((size_t)NN * 64 * 4);
    float* ybuf   = (float*)alloc((size_t)NN * 64 * 4);
    float* pooled = (float*)alloc((size_t)5 * NG * 64 * 4);
    float* stats  = (float*)alloc(1024 * 4);
    int* cnt  = (int*)alloc((size_t)NN * 4);
    int* off  = (int*)alloc((size_t)(NN + 1) * 4);
    int* cur  = (int*)alloc((size_t)NN * 4);
    int* csr  = (int*)alloc((size_t)NE * 4);
    int* bsum = (int*)alloc(512 * 4);

    k_init<<<512, 256, 0, stream>>>(pooled, stats, cnt);
    k_hist<<<2048, 256, 0, stream>>>(dst, cnt);
    k_scanA<<<NSCAN, SCAN_BLK, 0, stream>>>(cnt, off, bsum);
    k_scanB<<<1, 512, 0, stream>>>(bsum);
    k_scanC<<<512, 256, 0, stream>>>(off, bsum, cur);
    k_scatter<<<2048, 256, 0, stream>>>(src, dst, cur, csr);

    const float* hin = feat;
    for (int L = 0; L < 4; ++L) {
        float* s1 = stats + L * 256;
        float* s2 = s1 + 128;
        k_agg_g1<<<AGG_BLOCKS, 256, 0, stream>>>(hin, csr, off, W1 + L * 4096, ybuf, s1,
                                                 gid, (L == 0) ? pooled : nullptr);
        k_g2<<<AGG_BLOCKS, 256, 0, stream>>>(ybuf, s1, bn1g + L * 64, bn1b + L * 64,
                                             W2 + L * 4096, hbuf, s2);
        k_a2<<<AGG_BLOCKS, 256, 0, stream>>>(hbuf, s2, bn2g + L * 64, bn2b + L * 64,
                                             gid, pooled + (size_t)(L + 1) * NG * 64);
        hin = hbuf;
    }
    k_final<<<(NG * 16 + 255) / 256, 256, 0, stream>>>(pooled, pW, pb, out);
}